// Round 13
// baseline (405.153 us; speedup 1.0000x reference)
//
#include <hip/hip_runtime.h>

#define EPS_LN 1e-5f

typedef __attribute__((ext_vector_type(4))) float f32x4;
typedef __attribute__((ext_vector_type(4))) int i32x4;

// ---------------------------------------------------------------------------
// bf16 helpers
__device__ inline unsigned short f2bf_rne(float x) {
  unsigned int u = __float_as_uint(x);
  unsigned int r = u + 0x7fffu + ((u >> 16) & 1u);
  return (unsigned short)(r >> 16);
}

__device__ inline float4 bf4_to_f4(uint2 u) {
  float4 f;
  f.x = __uint_as_float(u.x << 16);
  f.y = __uint_as_float(u.x & 0xffff0000u);
  f.z = __uint_as_float(u.y << 16);
  f.w = __uint_as_float(u.y & 0xffff0000u);
  return f;
}

__device__ inline uint2 f4_to_bf4(float4 v) {
  uint2 o;
  o.x = (unsigned)f2bf_rne(v.x) | ((unsigned)f2bf_rne(v.y) << 16);
  o.y = (unsigned)f2bf_rne(v.z) | ((unsigned)f2bf_rne(v.w) << 16);
  return o;
}

// ---------------------------------------------------------------------------
// x (f32) -> H (bf16)
__global__ __launch_bounds__(256) void copy_bf16_kernel(const float4* __restrict__ in,
                                                        uint2* __restrict__ out, int n4) {
  int i = blockIdx.x * 256 + threadIdx.x;
  if (i < n4) out[i] = f4_to_bf4(in[i]);
}

// scatter mask_token (f32) into bf16 H rows listed in mn
__global__ __launch_bounds__(256) void mask_scatter_kernel(const int* __restrict__ mn,
                                                           const float* __restrict__ token,
                                                           unsigned short* __restrict__ H,
                                                           int nmask) {
  int gid = blockIdx.x * 256 + threadIdx.x;
  if (gid >= nmask * 32) return;
  int i = gid >> 5;
  int c4 = (gid & 31) << 2;
  int r = mn[i];
  float4 t = *(const float4*)(token + c4);
  *(uint2*)(H + (size_t)r * 128 + c4) = f4_to_bf4(t);
}

// ---------------------------------------------------------------------------
// CSR build: histogram of dst
__global__ __launch_bounds__(256) void hist_kernel(const int* __restrict__ dst,
                                                   int* __restrict__ deg, int nE) {
  int e = blockIdx.x * 256 + threadIdx.x;
  if (e < nE) atomicAdd(deg + dst[e], 1);
}

// ---- 3-phase parallel exclusive scan of deg[n] -> off[n+1] ----
#define SCAN_CHUNK 1024

__global__ __launch_bounds__(256) void blocksum_kernel(const int* __restrict__ deg,
                                                       int* __restrict__ bsum, int n) {
  __shared__ int red[256];
  int base = blockIdx.x * SCAN_CHUNK;
  int tid = threadIdx.x;
  int s = 0;
#pragma unroll
  for (int t = 0; t < SCAN_CHUNK / 256; ++t) {
    int g = base + tid + t * 256;
    if (g < n) s += deg[g];
  }
  red[tid] = s;
  __syncthreads();
  for (int ofs = 128; ofs > 0; ofs >>= 1) {
    if (tid < ofs) red[tid] += red[tid + ofs];
    __syncthreads();
  }
  if (tid == 0) bsum[blockIdx.x] = red[0];
}

__global__ __launch_bounds__(64) void bscan_kernel(const int* __restrict__ bsum,
                                                   int* __restrict__ bbase,
                                                   int* __restrict__ off_n, int nb) {
  int tid = threadIdx.x;
  int v = (tid < nb) ? bsum[tid] : 0;
  int incl = v;
#pragma unroll
  for (int ofs = 1; ofs < 64; ofs <<= 1) {
    int u = __shfl_up(incl, ofs, 64);
    if (tid >= ofs) incl += u;
  }
  if (tid < nb) bbase[tid] = incl - v;
  if (tid == nb - 1) off_n[0] = incl;
}

__global__ __launch_bounds__(256) void chunkscan_kernel(const int* __restrict__ deg,
                                                        const int* __restrict__ bbase,
                                                        int* __restrict__ off, int n) {
  __shared__ int part[256];
  int tid = threadIdx.x;
  int base = blockIdx.x * SCAN_CHUNK;
  int g0 = base + tid * 4;
  int loc[4];
  int s = 0;
#pragma unroll
  for (int j = 0; j < 4; ++j) {
    int g = g0 + j;
    int d = (g < n) ? deg[g] : 0;
    loc[j] = s;
    s += d;
  }
  part[tid] = s;
  __syncthreads();
  for (int ofs = 1; ofs < 256; ofs <<= 1) {
    int v = 0;
    if (tid >= ofs) v = part[tid - ofs];
    __syncthreads();
    if (tid >= ofs) part[tid] += v;
    __syncthreads();
  }
  int pre = (tid == 0) ? 0 : part[tid - 1];
  int b = bbase[blockIdx.x] + pre;
#pragma unroll
  for (int j = 0; j < 4; ++j) {
    int g = g0 + j;
    if (g < n) off[g] = b + loc[j];
  }
}

// ---------------------------------------------------------------------------
// Edge sort, two phases, low-contention per-node atomics:
// Phase A: random-write only a 4B permutation index.
__global__ __launch_bounds__(256) void perm_scatter_kernel(
    const int* __restrict__ dst, const int* __restrict__ off,
    int* __restrict__ cur, int* __restrict__ perm, int nE) {
  int e = blockIdx.x * 256 + threadIdx.x;
  if (e >= nE) return;
  int d = dst[e];
  int pos = off[d] + atomicAdd(cur + d, 1);
  perm[pos] = e;
}

// Phase B: sequential read of perm, gather src/ew, sequential write of esw.
__global__ __launch_bounds__(256) void esw_build_kernel(
    const int* __restrict__ perm, const int* __restrict__ src,
    const float* __restrict__ ew, int2* __restrict__ esw, int nE) {
  int i = blockIdx.x * 256 + threadIdx.x;
  if (i >= nE) return;
  int e = perm[i];
  esw[i] = make_int2(src[e], __float_as_int(ew[e]));
}

// ---------------------------------------------------------------------------
// per-node segment max over CSR, bf16 P -> bf16 neigh, f32 math.
// din/8 lanes per node, one uint4 (8 bf16) per lane. 4 independent chains.
__global__ __launch_bounds__(256) void neigh_csr_kernel(
    const unsigned short* __restrict__ P, const int* __restrict__ off,
    const int2* __restrict__ esw,
    unsigned short* __restrict__ neigh, int din, int lanes, int nN) {
  int gid = blockIdx.x * 256 + threadIdx.x;
  int v = gid / lanes;
  int c = (gid - v * lanes) << 3;
  if (v >= nN) return;
  int jlo = off[v], jhi = off[v + 1];
  float m[8];
#pragma unroll
  for (int t = 0; t < 8; ++t) m[t] = 0.f;
  float n1[8], n2[8], n3[8];
#pragma unroll
  for (int t = 0; t < 8; ++t) { n1[t] = 0.f; n2[t] = 0.f; n3[t] = 0.f; }
  int j = jlo;
  for (; j + 4 <= jhi; j += 4) {
    int2 e0 = esw[j], e1 = esw[j + 1], e2 = esw[j + 2], e3 = esw[j + 3];
    uint4 q0 = *(const uint4*)(P + (size_t)e0.x * din + c);
    uint4 q1 = *(const uint4*)(P + (size_t)e1.x * din + c);
    uint4 q2 = *(const uint4*)(P + (size_t)e2.x * din + c);
    uint4 q3 = *(const uint4*)(P + (size_t)e3.x * din + c);
    float w0 = __int_as_float(e0.y), w1 = __int_as_float(e1.y);
    float w2 = __int_as_float(e2.y), w3 = __int_as_float(e3.y);
    float4 a0 = bf4_to_f4(make_uint2(q0.x, q0.y)), b0 = bf4_to_f4(make_uint2(q0.z, q0.w));
    float4 a1 = bf4_to_f4(make_uint2(q1.x, q1.y)), b1 = bf4_to_f4(make_uint2(q1.z, q1.w));
    float4 a2 = bf4_to_f4(make_uint2(q2.x, q2.y)), b2 = bf4_to_f4(make_uint2(q2.z, q2.w));
    float4 a3 = bf4_to_f4(make_uint2(q3.x, q3.y)), b3 = bf4_to_f4(make_uint2(q3.z, q3.w));
    m[0] = fmaxf(m[0], a0.x * w0); m[1] = fmaxf(m[1], a0.y * w0);
    m[2] = fmaxf(m[2], a0.z * w0); m[3] = fmaxf(m[3], a0.w * w0);
    m[4] = fmaxf(m[4], b0.x * w0); m[5] = fmaxf(m[5], b0.y * w0);
    m[6] = fmaxf(m[6], b0.z * w0); m[7] = fmaxf(m[7], b0.w * w0);
    n1[0] = fmaxf(n1[0], a1.x * w1); n1[1] = fmaxf(n1[1], a1.y * w1);
    n1[2] = fmaxf(n1[2], a1.z * w1); n1[3] = fmaxf(n1[3], a1.w * w1);
    n1[4] = fmaxf(n1[4], b1.x * w1); n1[5] = fmaxf(n1[5], b1.y * w1);
    n1[6] = fmaxf(n1[6], b1.z * w1); n1[7] = fmaxf(n1[7], b1.w * w1);
    n2[0] = fmaxf(n2[0], a2.x * w2); n2[1] = fmaxf(n2[1], a2.y * w2);
    n2[2] = fmaxf(n2[2], a2.z * w2); n2[3] = fmaxf(n2[3], a2.w * w2);
    n2[4] = fmaxf(n2[4], b2.x * w2); n2[5] = fmaxf(n2[5], b2.y * w2);
    n2[6] = fmaxf(n2[6], b2.z * w2); n2[7] = fmaxf(n2[7], b2.w * w2);
    n3[0] = fmaxf(n3[0], a3.x * w3); n3[1] = fmaxf(n3[1], a3.y * w3);
    n3[2] = fmaxf(n3[2], a3.z * w3); n3[3] = fmaxf(n3[3], a3.w * w3);
    n3[4] = fmaxf(n3[4], b3.x * w3); n3[5] = fmaxf(n3[5], b3.y * w3);
    n3[6] = fmaxf(n3[6], b3.z * w3); n3[7] = fmaxf(n3[7], b3.w * w3);
  }
  for (; j < jhi; ++j) {
    int2 e = esw[j];
    float w = __int_as_float(e.y);
    uint4 q = *(const uint4*)(P + (size_t)e.x * din + c);
    float4 a = bf4_to_f4(make_uint2(q.x, q.y)), b = bf4_to_f4(make_uint2(q.z, q.w));
    m[0] = fmaxf(m[0], a.x * w); m[1] = fmaxf(m[1], a.y * w);
    m[2] = fmaxf(m[2], a.z * w); m[3] = fmaxf(m[3], a.w * w);
    m[4] = fmaxf(m[4], b.x * w); m[5] = fmaxf(m[5], b.y * w);
    m[6] = fmaxf(m[6], b.z * w); m[7] = fmaxf(m[7], b.w * w);
  }
#pragma unroll
  for (int t = 0; t < 8; ++t) m[t] = fmaxf(fmaxf(m[t], n1[t]), fmaxf(n2[t], n3[t]));
  uint2 o0 = f4_to_bf4(make_float4(m[0], m[1], m[2], m[3]));
  uint2 o1 = f4_to_bf4(make_float4(m[4], m[5], m[6], m[7]));
  *(uint4*)(neigh + (size_t)v * din + c) = make_uint4(o0.x, o0.y, o1.x, o1.y);
}

// ---------------------------------------------------------------------------
// small weight-combine: C[M][N] = A[M][K] @ B[K][N]  (row-major, tiny)
__global__ __launch_bounds__(256) void matmul_small_kernel(const float* __restrict__ A,
                                                           const float* __restrict__ B,
                                                           float* __restrict__ C,
                                                           int M, int K, int N) {
  int idx = blockIdx.x * 256 + threadIdx.x;
  if (idx >= M * N) return;
  int o = idx / N, i = idx - o * N;
  float s = 0.f;
  for (int k = 0; k < K; ++k) s += A[o * K + k] * B[k * N + i];
  C[idx] = s;
}

// ---------------------------------------------------------------------------
__device__ inline void mfma_b16(f32x4& acc, i32x4 a, i32x4 b) {
  asm volatile("v_mfma_f32_16x16x32_bf16 %0, %1, %2, %0"
               : "+v"(acc)
               : "v"(a), "v"(b));
}

__device__ inline void split_bf16(float x, unsigned short& hi, unsigned short& lo) {
  unsigned int bits = __float_as_uint(x);
  hi = (unsigned short)(bits >> 16);
  float hif = __uint_as_float((unsigned int)hi << 16);
  float res = x - hif;
  lo = (unsigned short)(__float_as_uint(res) >> 16);
}

// one-shot split of all weight matrices into bf16 hi/lo planes
struct SplitWArgs {
  const float* src[12];
  unsigned short* dh[12];
  unsigned short* dl[12];
  int n[12];
};

__global__ __launch_bounds__(256) void split_w_kernel(SplitWArgs a) {
  int m = blockIdx.y;
  int i = (blockIdx.x * 256 + threadIdx.x) * 4;
  if (i >= a.n[m]) return;
  float4 v = *(const float4*)(a.src[m] + i);
  unsigned short h[4], l[4];
  split_bf16(v.x, h[0], l[0]);
  split_bf16(v.y, h[1], l[1]);
  split_bf16(v.z, h[2], l[2]);
  split_bf16(v.w, h[3], l[3]);
  *(uint2*)(a.dh[m] + i) = make_uint2((unsigned)h[0] | ((unsigned)h[1] << 16),
                                      (unsigned)h[2] | ((unsigned)h[3] << 16));
  *(uint2*)(a.dl[m] + i) = make_uint2((unsigned)l[0] | ((unsigned)l[1] << 16),
                                      (unsigned)l[2] | ((unsigned)l[3] << 16));
}

// ---------------------------------------------------------------------------
// Register-resident-W MFMA GEMM (no LDS, no barriers), bf16 activations.
//   C_bf16[nrows, BN] = act( A1@W1^T (+A2@W2^T) + bias )
// 2x2 wave grid: wave wv -> (wr=wv&1: rows wr*32..+31, wc=wv>>1: cols wc*BN/2..).
// W hi/lo fragments preloaded into registers per pass (L2-resident planes).
// A fragments loaded directly from global per K-chunk.
// v_mfma_f32_16x16x32_bf16: A[row=lane&15][k=8*(lane>>4)+e],
//                           B[k=8*(lane>>4)+e][col=lane&15],
//                           D[row=4*(lane>>4)+q][col=lane&15].
template <int TNT, int K>  // BN = TNT*16
__global__ __launch_bounds__(256) void mfma_gemm_kernel(
    const unsigned short* __restrict__ A1, const unsigned short* __restrict__ Wh1,
    const unsigned short* __restrict__ Wl1,
    const unsigned short* __restrict__ A2, const unsigned short* __restrict__ Wh2,
    const unsigned short* __restrict__ Wl2,
    const float* __restrict__ bias, int relu,
    unsigned short* __restrict__ C, int nrows) {
  constexpr int BN = TNT * 16;
  constexpr int BN2 = BN / 2;
  constexpr int NC = TNT / 2;  // col fragments per wave
  constexpr int KC = K / 32;   // k chunks

  const int tid = threadIdx.x;
  const int lane = tid & 63;
  const int wv = tid >> 6;
  const int wr = wv & 1;       // row half
  const int wc = wv >> 1;      // col half
  const int lr = lane & 15;
  const int lg = lane >> 4;
  const int row0 = blockIdx.x * 64;

  f32x4 acc[2][NC];
#pragma unroll
  for (int rf = 0; rf < 2; ++rf)
#pragma unroll
    for (int cf = 0; cf < NC; ++cf) acc[rf][cf] = (f32x4)(0.f);

  for (int pass = 0; pass < 2; ++pass) {
    const unsigned short* A = pass ? A2 : A1;
    if (A == nullptr) continue;  // uniform across block
    const unsigned short* Whp = pass ? Wh2 : Wh1;
    const unsigned short* Wlp = pass ? Wl2 : Wl1;

    // preload W fragments into registers (compile-time indexed)
    i32x4 wh[NC][KC], wl[NC][KC];
#pragma unroll
    for (int cf = 0; cf < NC; ++cf)
#pragma unroll
      for (int kc = 0; kc < KC; ++kc) {
        size_t o = (size_t)(wc * BN2 + cf * 16 + lr) * K + kc * 32 + lg * 8;
        wh[cf][kc] = *(const i32x4*)(Whp + o);
        wl[cf][kc] = *(const i32x4*)(Wlp + o);
      }

    const int gr0 = row0 + wr * 32 + lr;        // rf=0 row
    const int gr1 = gr0 + 16;                   // rf=1 row
#pragma unroll
    for (int kc = 0; kc < KC; ++kc) {
      i32x4 a0 = (i32x4)(0), a1 = (i32x4)(0);
      if (gr0 < nrows) a0 = *(const i32x4*)(A + (size_t)gr0 * K + kc * 32 + lg * 8);
      if (gr1 < nrows) a1 = *(const i32x4*)(A + (size_t)gr1 * K + kc * 32 + lg * 8);
#pragma unroll
      for (int cf = 0; cf < NC; ++cf) {
        mfma_b16(acc[0][cf], a0, wh[cf][kc]);
        mfma_b16(acc[0][cf], a0, wl[cf][kc]);
        mfma_b16(acc[1][cf], a1, wh[cf][kc]);
        mfma_b16(acc[1][cf], a1, wl[cf][kc]);
      }
    }
  }

  // cover MFMA->VALU write latency (asm is opaque to the scheduler)
  asm volatile("s_nop 7\n\ts_nop 7" ::);

#pragma unroll
  for (int rf = 0; rf < 2; ++rf)
#pragma unroll
    for (int cf = 0; cf < NC; ++cf) {
      int c = wc * BN2 + cf * 16 + lr;
      float bv = bias ? bias[c] : 0.f;
#pragma unroll
      for (int q = 0; q < 4; ++q) {
        int r = row0 + wr * 32 + rf * 16 + lg * 4 + q;
        if (r < nrows) {
          float v = acc[rf][cf][q] + bv;
          if (relu) v = fmaxf(v, 0.f);
          C[(size_t)r * BN + c] = f2bf_rne(v);
        }
      }
    }
}

// ---------------------------------------------------------------------------
// z = H @ Wnp^T + bnp  (H: [n,64] bf16, Wnp: [16,64] f32) then LayerNorm(16)
__global__ __launch_bounds__(256) void nodepred_ln_kernel(
    const unsigned short* __restrict__ H, const float* __restrict__ Wnp,
    const float* __restrict__ bnp, const float* __restrict__ g,
    const float* __restrict__ lb, float* __restrict__ out, int nrows) {
  __shared__ float hs[16][64];
  int tid = threadIdx.x;
  int row0 = blockIdx.x * 16;
  {
    int r = tid >> 4;
    int c4 = (tid & 15) << 2;
    int gr = row0 + r;
    float4 v = make_float4(0.f, 0.f, 0.f, 0.f);
    if (gr < nrows) v = bf4_to_f4(*(const uint2*)(H + (size_t)gr * 64 + c4));
    *(float4*)&hs[r][c4] = v;
  }
  __syncthreads();
  int r = tid >> 4, j = tid & 15;
  float z = bnp[j];
  const float* wrow = Wnp + j * 64;
#pragma unroll 8
  for (int k = 0; k < 64; ++k) z += hs[r][k] * wrow[k];
  float s = z, s2 = z * z;
#pragma unroll
  for (int m = 1; m < 16; m <<= 1) {
    s += __shfl_xor(s, m, 16);
    s2 += __shfl_xor(s2, m, 16);
  }
  float mu = s * (1.f / 16.f);
  float var = s2 * (1.f / 16.f) - mu * mu;
  float o = (z - mu) * rsqrtf(var + EPS_LN) * g[j] + lb[j];
  int gr = row0 + r;
  if (gr < nrows) out[(size_t)gr * 16 + j] = o;
}

// ---------------------------------------------------------------------------
// out1[i] = f32(R_bf16[mn[i]]), out2[i] = X_f32[mn[i]]   (rows of 128)
__global__ __launch_bounds__(256) void gather_out_kernel(
    const int* __restrict__ mn, const unsigned short* __restrict__ R,
    const float* __restrict__ X,
    float* __restrict__ o1, float* __restrict__ o2, int nmask) {
  int gid = blockIdx.x * 256 + threadIdx.x;
  if (gid >= nmask * 32) return;
  int i = gid >> 5, c4 = (gid & 31) << 2;
  int r = mn[i];
  float4 rv = bf4_to_f4(*(const uint2*)(R + (size_t)r * 128 + c4));
  *(float4*)(o1 + (size_t)i * 128 + c4) = rv;
  *(float4*)(o2 + (size_t)i * 128 + c4) = *(const float4*)(X + (size_t)r * 128 + c4);
}

// ---------------------------------------------------------------------------
static void launch_gemm(const unsigned short* A1, const unsigned short* Wh1,
                        const unsigned short* Wl1,
                        const unsigned short* A2, const unsigned short* Wh2,
                        const unsigned short* Wl2,
                        const float* bias, int relu,
                        unsigned short* C, int m, int K, int nrows, hipStream_t s) {
  int blocks = (nrows + 63) / 64;
#define GEMM_CASE(TNT, KK)                                                   \
  mfma_gemm_kernel<TNT, KK><<<blocks, 256, 0, s>>>(A1, Wh1, Wl1, A2, Wh2,    \
                                                   Wl2, bias, relu, C, nrows)
  if (m == 128 && K == 128) GEMM_CASE(8, 128);
  else if (m == 96 && K == 128) GEMM_CASE(6, 128);
  else if (m == 96 && K == 96) GEMM_CASE(6, 96);
  else if (m == 64 && K == 96) GEMM_CASE(4, 96);
  else if (m == 64 && K == 64) GEMM_CASE(4, 64);
  else if (m == 96 && K == 64) GEMM_CASE(6, 64);
  else if (m == 128 && K == 96) GEMM_CASE(8, 96);
#undef GEMM_CASE
}

extern "C" void kernel_launch(void* const* d_in, const int* in_sizes, int n_in,
                              void* d_out, int out_size, void* d_ws, size_t ws_size,
                              hipStream_t stream) {
  const float* x = (const float*)d_in[0];
  const int* src = (const int*)d_in[1];
  const int* dst = (const int*)d_in[2];
  const float* ew = (const float*)d_in[3];
  const int* mn = (const int*)d_in[4];
  const float* token = (const float*)d_in[5];

  const float* W[20];
  for (int i = 0; i < 20; ++i) W[i] = (const float*)d_in[6 + i];
  const float* W_e2d = (const float*)d_in[26];
  const float* Wnp = (const float*)d_in[27];
  const float* bnp = (const float*)d_in[28];
  const float* ln_g = (const float*)d_in[29];
  const float* ln_b = (const float*)d_in[30];

  const int Nn = in_sizes[0] / 128;   // 50000
  const int E = in_sizes[1];          // 600000
  const int nmask = in_sizes[4];      // 10000
  const int nb = (Nn + SCAN_CHUNK - 1) / SCAN_CHUNK;  // 49

  // workspace layout (bf16 activations)
  unsigned short* bufA = (unsigned short*)d_ws;            // N*128 bf16
  unsigned short* bufB = bufA + (size_t)Nn * 128;          // N*128 bf16
  unsigned short* pool16 = bufB + (size_t)Nn * 128;        // N*128 bf16
  unsigned short* neigh16 = pool16 + (size_t)Nn * 128;     // N*128 bf16
  int* deg = (int*)(neigh16 + (size_t)Nn * 128);           // N int
  int* cur = deg + Nn;                                     // N int
  int2* esw = (int2*)(cur + Nn);                           // E int2
  int* off = (int*)(esw + E);                              // N+1 int
  int* bsum = off + Nn + 1;                                // 64 int
  int* bbase = bsum + 64;                                  // 64 int
  int* perm = bbase + 64;                                  // E int
  float* WpP = (float*)(perm + E);                         // 64*64 f32
  float* WsP = WpP + 64 * 64;                              // 96*64 f32
  unsigned short* wplanes =
      (unsigned short*)(((uintptr_t)(WsP + 96 * 64) + 15) & ~(uintptr_t)15);

  // ---- fold encoder_to_decoder into dec0 weights (tiny) ----
  matmul_small_kernel<<<(64 * 64 + 255) / 256, 256, 0, stream>>>(W[10], W_e2d, WpP, 64, 64, 64);
  matmul_small_kernel<<<(96 * 64 + 255) / 256, 256, 0, stream>>>(W[12], W_e2d, WsP, 96, 64, 64);

  // ---- one-shot split of all GEMM weights into bf16 hi/lo planes ----
  const int msz[12] = {128 * 128, 96 * 128, 96 * 128, 96 * 96, 64 * 96, 64 * 96,
                       64 * 64,  96 * 64,  96 * 64,  96 * 96, 128 * 96, 128 * 96};
  const float* msrc[12] = {W[0], W[2], W[3], W[5], W[7], W[8],
                           WpP,  WsP,  W[13], W[15], W[17], W[18]};
  int mtot = 0;
  int moff[12];
  for (int i = 0; i < 12; ++i) { moff[i] = mtot; mtot += msz[i]; }
  unsigned short* wh_[12];
  unsigned short* wl_[12];
  SplitWArgs sa;
  for (int i = 0; i < 12; ++i) {
    wh_[i] = wplanes + moff[i];
    wl_[i] = wplanes + mtot + moff[i];
    sa.src[i] = msrc[i];
    sa.dh[i] = wh_[i];
    sa.dl[i] = wl_[i];
    sa.n[i] = msz[i];
  }
  {
    dim3 grid((128 * 128 / 4 + 255) / 256, 12);
    split_w_kernel<<<grid, 256, 0, stream>>>(sa);
  }

  // ---- CSR build (once; graph identical across layers) ----
  hipMemsetAsync(deg, 0, (size_t)Nn * 2 * sizeof(int), stream);  // deg + cur
  hist_kernel<<<(E + 255) / 256, 256, 0, stream>>>(dst, deg, E);
  blocksum_kernel<<<nb, 256, 0, stream>>>(deg, bsum, Nn);
  bscan_kernel<<<1, 64, 0, stream>>>(bsum, bbase, off + Nn, nb);
  chunkscan_kernel<<<nb, 256, 0, stream>>>(deg, bbase, off, Nn);
  perm_scatter_kernel<<<(E + 255) / 256, 256, 0, stream>>>(dst, off, cur, perm, E);
  esw_build_kernel<<<(E + 255) / 256, 256, 0, stream>>>(perm, src, ew, esw, E);

  // h = bf16(x); h[mask_nodes] = bf16(token)
  {
    int n4 = Nn * 128 / 4;
    copy_bf16_kernel<<<(n4 + 255) / 256, 256, 0, stream>>>((const float4*)x, (uint2*)bufA, n4);
    mask_scatter_kernel<<<(nmask * 32 + 255) / 256, 256, 0, stream>>>(mn, token, bufA, nmask);
  }

  // plane indices {wp, ws, wn} per layer
  auto run_sage = [&](int ip, int is, int in_, const float* bp, const float* b,
                      int din, int dout) {
    // p = relu(h @ Wp^T + bp)  -> bf16 pool
    launch_gemm(bufA, wh_[ip], wl_[ip], nullptr, nullptr, nullptr,
                bp, 1, pool16, din, din, Nn, stream);
    // neigh = segment_max(p[src]*ew, dst), bf16; zero-degree rows -> 0
    int lanes = din >> 3;
    long long tot = (long long)Nn * lanes;
    int nblocks = (int)((tot + 255) / 256);
    neigh_csr_kernel<<<nblocks, 256, 0, stream>>>(pool16, off, esw, neigh16, din, lanes, Nn);
    // out = relu(h @ Ws^T + neigh @ Wn^T + b)  -> bf16
    launch_gemm(bufA, wh_[is], wl_[is], neigh16, wh_[in_], wl_[in_],
                b, 1, bufB, dout, din, Nn, stream);
    unsigned short* t = bufA; bufA = bufB; bufB = t;
  };

  // encoder
  run_sage(0, 1, 2, W[1], W[4], 128, 96);   // enc0
  run_sage(3, 4, 5, W[6], W[9], 96, 64);    // enc1

  // node_pred + layernorm -> n_scores (out section 3)
  float* out_r = (float*)d_out;
  float* out_x = out_r + (size_t)nmask * 128;
  float* out_ns = out_x + (size_t)nmask * 128;
  nodepred_ln_kernel<<<(Nn + 15) / 16, 256, 0, stream>>>(bufA, Wnp, bnp, ln_g, ln_b, out_ns, Nn);

  // decoder (e2d folded into dec0 weights)
  run_sage(6, 7, 8, W[11], W[14], 64, 96);     // dec0 (+e2d)
  run_sage(9, 10, 11, W[16], W[19], 96, 128);  // dec1

  // outputs 1 & 2
  gather_out_kernel<<<(nmask * 32 + 255) / 256, 256, 0, stream>>>(mn, bufA, x, out_r, out_x, nmask);
}

// Round 14
// 369.103 us; speedup vs baseline: 1.0977x; 1.0977x over previous
//
#include <hip/hip_runtime.h>

#define EPS_LN 1e-5f

typedef __attribute__((ext_vector_type(4))) float f32x4;
typedef __attribute__((ext_vector_type(4))) int i32x4;

// ---------------------------------------------------------------------------
// bf16 helpers
__device__ inline unsigned short f2bf_rne(float x) {
  unsigned int u = __float_as_uint(x);
  unsigned int r = u + 0x7fffu + ((u >> 16) & 1u);
  return (unsigned short)(r >> 16);
}

__device__ inline float4 bf4_to_f4(uint2 u) {
  float4 f;
  f.x = __uint_as_float(u.x << 16);
  f.y = __uint_as_float(u.x & 0xffff0000u);
  f.z = __uint_as_float(u.y << 16);
  f.w = __uint_as_float(u.y & 0xffff0000u);
  return f;
}

__device__ inline uint2 f4_to_bf4(float4 v) {
  uint2 o;
  o.x = (unsigned)f2bf_rne(v.x) | ((unsigned)f2bf_rne(v.y) << 16);
  o.y = (unsigned)f2bf_rne(v.z) | ((unsigned)f2bf_rne(v.w) << 16);
  return o;
}

// ---------------------------------------------------------------------------
// x (f32) -> H (bf16)
__global__ __launch_bounds__(256) void copy_bf16_kernel(const float4* __restrict__ in,
                                                        uint2* __restrict__ out, int n4) {
  int i = blockIdx.x * 256 + threadIdx.x;
  if (i < n4) out[i] = f4_to_bf4(in[i]);
}

// scatter mask_token (f32) into bf16 H rows listed in mn
__global__ __launch_bounds__(256) void mask_scatter_kernel(const int* __restrict__ mn,
                                                           const float* __restrict__ token,
                                                           unsigned short* __restrict__ H,
                                                           int nmask) {
  int gid = blockIdx.x * 256 + threadIdx.x;
  if (gid >= nmask * 32) return;
  int i = gid >> 5;
  int c4 = (gid & 31) << 2;
  int r = mn[i];
  float4 t = *(const float4*)(token + c4);
  *(uint2*)(H + (size_t)r * 128 + c4) = f4_to_bf4(t);
}

// ---------------------------------------------------------------------------
// CSR build: histogram of dst
__global__ __launch_bounds__(256) void hist_kernel(const int* __restrict__ dst,
                                                   int* __restrict__ deg, int nE) {
  int e = blockIdx.x * 256 + threadIdx.x;
  if (e < nE) atomicAdd(deg + dst[e], 1);
}

// ---- 3-phase parallel exclusive scan of deg[n] -> off[n+1] ----
#define SCAN_CHUNK 1024

__global__ __launch_bounds__(256) void blocksum_kernel(const int* __restrict__ deg,
                                                       int* __restrict__ bsum, int n) {
  __shared__ int red[256];
  int base = blockIdx.x * SCAN_CHUNK;
  int tid = threadIdx.x;
  int s = 0;
#pragma unroll
  for (int t = 0; t < SCAN_CHUNK / 256; ++t) {
    int g = base + tid + t * 256;
    if (g < n) s += deg[g];
  }
  red[tid] = s;
  __syncthreads();
  for (int ofs = 128; ofs > 0; ofs >>= 1) {
    if (tid < ofs) red[tid] += red[tid + ofs];
    __syncthreads();
  }
  if (tid == 0) bsum[blockIdx.x] = red[0];
}

__global__ __launch_bounds__(64) void bscan_kernel(const int* __restrict__ bsum,
                                                   int* __restrict__ bbase,
                                                   int* __restrict__ off_n, int nb) {
  int tid = threadIdx.x;
  int v = (tid < nb) ? bsum[tid] : 0;
  int incl = v;
#pragma unroll
  for (int ofs = 1; ofs < 64; ofs <<= 1) {
    int u = __shfl_up(incl, ofs, 64);
    if (tid >= ofs) incl += u;
  }
  if (tid < nb) bbase[tid] = incl - v;
  if (tid == nb - 1) off_n[0] = incl;
}

__global__ __launch_bounds__(256) void chunkscan_kernel(const int* __restrict__ deg,
                                                        const int* __restrict__ bbase,
                                                        int* __restrict__ off, int n) {
  __shared__ int part[256];
  int tid = threadIdx.x;
  int base = blockIdx.x * SCAN_CHUNK;
  int g0 = base + tid * 4;
  int loc[4];
  int s = 0;
#pragma unroll
  for (int j = 0; j < 4; ++j) {
    int g = g0 + j;
    int d = (g < n) ? deg[g] : 0;
    loc[j] = s;
    s += d;
  }
  part[tid] = s;
  __syncthreads();
  for (int ofs = 1; ofs < 256; ofs <<= 1) {
    int v = 0;
    if (tid >= ofs) v = part[tid - ofs];
    __syncthreads();
    if (tid >= ofs) part[tid] += v;
    __syncthreads();
  }
  int pre = (tid == 0) ? 0 : part[tid - 1];
  int b = bbase[blockIdx.x] + pre;
#pragma unroll
  for (int j = 0; j < 4; ++j) {
    int g = g0 + j;
    if (g < n) off[g] = b + loc[j];
  }
}

// scatter edges into dst-sorted order; (src, ew-bits) packed -> one line/edge
// (single-phase, per-node atomics: ~12 edges/counter, low contention)
__global__ __launch_bounds__(256) void scatter_kernel(const int* __restrict__ src,
                                                      const int* __restrict__ dst,
                                                      const float* __restrict__ ew,
                                                      const int* __restrict__ off,
                                                      int* __restrict__ cur,
                                                      int2* __restrict__ esw, int nE) {
  int e = blockIdx.x * 256 + threadIdx.x;
  if (e >= nE) return;
  int d = dst[e];
  int pos = off[d] + atomicAdd(cur + d, 1);
  esw[pos] = make_int2(src[e], __float_as_int(ew[e]));
}

// ---------------------------------------------------------------------------
// per-node segment max over CSR, bf16 P -> bf16 neigh, f32 math.
// din/8 lanes per node, one uint4 (8 bf16) per lane. 4 independent chains.
__global__ __launch_bounds__(256) void neigh_csr_kernel(
    const unsigned short* __restrict__ P, const int* __restrict__ off,
    const int2* __restrict__ esw,
    unsigned short* __restrict__ neigh, int din, int lanes, int nN) {
  int gid = blockIdx.x * 256 + threadIdx.x;
  int v = gid / lanes;
  int c = (gid - v * lanes) << 3;
  if (v >= nN) return;
  int jlo = off[v], jhi = off[v + 1];
  float m[8];
#pragma unroll
  for (int t = 0; t < 8; ++t) m[t] = 0.f;
  float n1[8], n2[8], n3[8];
#pragma unroll
  for (int t = 0; t < 8; ++t) { n1[t] = 0.f; n2[t] = 0.f; n3[t] = 0.f; }
  int j = jlo;
  for (; j + 4 <= jhi; j += 4) {
    int2 e0 = esw[j], e1 = esw[j + 1], e2 = esw[j + 2], e3 = esw[j + 3];
    uint4 q0 = *(const uint4*)(P + (size_t)e0.x * din + c);
    uint4 q1 = *(const uint4*)(P + (size_t)e1.x * din + c);
    uint4 q2 = *(const uint4*)(P + (size_t)e2.x * din + c);
    uint4 q3 = *(const uint4*)(P + (size_t)e3.x * din + c);
    float w0 = __int_as_float(e0.y), w1 = __int_as_float(e1.y);
    float w2 = __int_as_float(e2.y), w3 = __int_as_float(e3.y);
    float4 a0 = bf4_to_f4(make_uint2(q0.x, q0.y)), b0 = bf4_to_f4(make_uint2(q0.z, q0.w));
    float4 a1 = bf4_to_f4(make_uint2(q1.x, q1.y)), b1 = bf4_to_f4(make_uint2(q1.z, q1.w));
    float4 a2 = bf4_to_f4(make_uint2(q2.x, q2.y)), b2 = bf4_to_f4(make_uint2(q2.z, q2.w));
    float4 a3 = bf4_to_f4(make_uint2(q3.x, q3.y)), b3 = bf4_to_f4(make_uint2(q3.z, q3.w));
    m[0] = fmaxf(m[0], a0.x * w0); m[1] = fmaxf(m[1], a0.y * w0);
    m[2] = fmaxf(m[2], a0.z * w0); m[3] = fmaxf(m[3], a0.w * w0);
    m[4] = fmaxf(m[4], b0.x * w0); m[5] = fmaxf(m[5], b0.y * w0);
    m[6] = fmaxf(m[6], b0.z * w0); m[7] = fmaxf(m[7], b0.w * w0);
    n1[0] = fmaxf(n1[0], a1.x * w1); n1[1] = fmaxf(n1[1], a1.y * w1);
    n1[2] = fmaxf(n1[2], a1.z * w1); n1[3] = fmaxf(n1[3], a1.w * w1);
    n1[4] = fmaxf(n1[4], b1.x * w1); n1[5] = fmaxf(n1[5], b1.y * w1);
    n1[6] = fmaxf(n1[6], b1.z * w1); n1[7] = fmaxf(n1[7], b1.w * w1);
    n2[0] = fmaxf(n2[0], a2.x * w2); n2[1] = fmaxf(n2[1], a2.y * w2);
    n2[2] = fmaxf(n2[2], a2.z * w2); n2[3] = fmaxf(n2[3], a2.w * w2);
    n2[4] = fmaxf(n2[4], b2.x * w2); n2[5] = fmaxf(n2[5], b2.y * w2);
    n2[6] = fmaxf(n2[6], b2.z * w2); n2[7] = fmaxf(n2[7], b2.w * w2);
    n3[0] = fmaxf(n3[0], a3.x * w3); n3[1] = fmaxf(n3[1], a3.y * w3);
    n3[2] = fmaxf(n3[2], a3.z * w3); n3[3] = fmaxf(n3[3], a3.w * w3);
    n3[4] = fmaxf(n3[4], b3.x * w3); n3[5] = fmaxf(n3[5], b3.y * w3);
    n3[6] = fmaxf(n3[6], b3.z * w3); n3[7] = fmaxf(n3[7], b3.w * w3);
  }
  for (; j < jhi; ++j) {
    int2 e = esw[j];
    float w = __int_as_float(e.y);
    uint4 q = *(const uint4*)(P + (size_t)e.x * din + c);
    float4 a = bf4_to_f4(make_uint2(q.x, q.y)), b = bf4_to_f4(make_uint2(q.z, q.w));
    m[0] = fmaxf(m[0], a.x * w); m[1] = fmaxf(m[1], a.y * w);
    m[2] = fmaxf(m[2], a.z * w); m[3] = fmaxf(m[3], a.w * w);
    m[4] = fmaxf(m[4], b.x * w); m[5] = fmaxf(m[5], b.y * w);
    m[6] = fmaxf(m[6], b.z * w); m[7] = fmaxf(m[7], b.w * w);
  }
#pragma unroll
  for (int t = 0; t < 8; ++t) m[t] = fmaxf(fmaxf(m[t], n1[t]), fmaxf(n2[t], n3[t]));
  uint2 o0 = f4_to_bf4(make_float4(m[0], m[1], m[2], m[3]));
  uint2 o1 = f4_to_bf4(make_float4(m[4], m[5], m[6], m[7]));
  *(uint4*)(neigh + (size_t)v * din + c) = make_uint4(o0.x, o0.y, o1.x, o1.y);
}

// ---------------------------------------------------------------------------
// small weight-combine: C[M][N] = A[M][K] @ B[K][N]  (row-major, tiny)
__global__ __launch_bounds__(256) void matmul_small_kernel(const float* __restrict__ A,
                                                           const float* __restrict__ B,
                                                           float* __restrict__ C,
                                                           int M, int K, int N) {
  int idx = blockIdx.x * 256 + threadIdx.x;
  if (idx >= M * N) return;
  int o = idx / N, i = idx - o * N;
  float s = 0.f;
  for (int k = 0; k < K; ++k) s += A[o * K + k] * B[k * N + i];
  C[idx] = s;
}

// ---------------------------------------------------------------------------
__device__ inline void mfma_b16(f32x4& acc, i32x4 a, i32x4 b) {
  asm volatile("v_mfma_f32_16x16x32_bf16 %0, %1, %2, %0"
               : "+v"(acc)
               : "v"(a), "v"(b));
}

__device__ inline void split_bf16(float x, unsigned short& hi, unsigned short& lo) {
  unsigned int bits = __float_as_uint(x);
  hi = (unsigned short)(bits >> 16);
  float hif = __uint_as_float((unsigned int)hi << 16);
  float res = x - hif;
  lo = (unsigned short)(__float_as_uint(res) >> 16);
}

// one-shot split of all weight matrices into bf16 hi/lo planes
struct SplitWArgs {
  const float* src[12];
  unsigned short* dh[12];
  unsigned short* dl[12];
  int n[12];
};

__global__ __launch_bounds__(256) void split_w_kernel(SplitWArgs a) {
  int m = blockIdx.y;
  int i = (blockIdx.x * 256 + threadIdx.x) * 4;
  if (i >= a.n[m]) return;
  float4 v = *(const float4*)(a.src[m] + i);
  unsigned short h[4], l[4];
  split_bf16(v.x, h[0], l[0]);
  split_bf16(v.y, h[1], l[1]);
  split_bf16(v.z, h[2], l[2]);
  split_bf16(v.w, h[3], l[3]);
  *(uint2*)(a.dh[m] + i) = make_uint2((unsigned)h[0] | ((unsigned)h[1] << 16),
                                      (unsigned)h[2] | ((unsigned)h[3] << 16));
  *(uint2*)(a.dl[m] + i) = make_uint2((unsigned)l[0] | ((unsigned)l[1] << 16),
                                      (unsigned)l[2] | ((unsigned)l[3] << 16));
}

// ---------------------------------------------------------------------------
// MFMA GEMM, bf16 activations: C_bf16[nrows,BN] = act( A1@W1^T (+A2@W2^T) +bias )
// A bf16 in global, fragments loaded DIRECTLY from global (no A staging).
// W pre-split hi/lo planes in LDS; 2-term MFMA (a*Wh + a*Wl) keeps W ~f32.
// Block: 256 thr = 4 waves; tile 64 rows x BN; wave w owns rows w*16..w*16+15.
// v_mfma_f32_16x16x32_bf16: A[row=lane&15][k=8*(lane>>4)+e],
//                           B[k=8*(lane>>4)+e][col=lane&15],
//                           D[row=4*(lane>>4)+q][col=lane&15].
template <int TNT>  // BN = TNT*16
__global__ __launch_bounds__(256) void mfma_gemm_kernel(
    const unsigned short* __restrict__ A1, const unsigned short* __restrict__ Wh1,
    const unsigned short* __restrict__ Wl1, int k1,
    const unsigned short* __restrict__ A2, const unsigned short* __restrict__ Wh2,
    const unsigned short* __restrict__ Wl2, int k2,
    const float* __restrict__ bias, int relu,
    unsigned short* __restrict__ C, int nrows) {
  constexpr int BN = TNT * 16;
  constexpr int WS = 136;  // W LDS row stride (ushort)
  __shared__ __align__(16) unsigned short Wh[BN][WS];
  __shared__ __align__(16) unsigned short Wl[BN][WS];

  const int tid = threadIdx.x;
  const int lane = tid & 63;
  const int wv = tid >> 6;      // wave 0..3 -> row band wv*16
  const int lr = lane & 15;     // frag row (A) / col (B,D)
  const int lg = lane >> 4;     // k-granule 0..3
  const int row0 = blockIdx.x * 64;
  const int gra = row0 + wv * 16 + lr;   // this lane's A row

  f32x4 acc[TNT];
#pragma unroll
  for (int t = 0; t < TNT; ++t) acc[t] = (f32x4)(0.f);

  for (int pass = 0; pass < 2; ++pass) {
    const unsigned short* A = pass ? A2 : A1;
    if (A == nullptr) continue;  // uniform across block
    const unsigned short* Whp = pass ? Wh2 : Wh1;
    const unsigned short* Wlp = pass ? Wl2 : Wl1;
    const int K = pass ? k2 : k1;

    if (pass) __syncthreads();  // protect previous pass's W reads
    {
      int tot8 = BN * K / 8;
      for (int i = tid; i < tot8; i += 256) {
        int e0 = i * 8;
        int col = e0 / K;
        int kk = e0 - col * K;
        *(uint4*)&Wh[col][kk] = *(const uint4*)(Whp + e0);
        *(uint4*)&Wl[col][kk] = *(const uint4*)(Wlp + e0);
      }
    }
    __syncthreads();

    for (int cb = 0; cb < K; cb += 32) {
      i32x4 a_h = (i32x4)(0);
      if (gra < nrows) a_h = *(const i32x4*)(A + (size_t)gra * K + cb + lg * 8);
#pragma unroll
      for (int t = 0; t < TNT; ++t) {
        i32x4 b_h = *(const i32x4*)&Wh[t * 16 + lr][cb + lg * 8];
        i32x4 b_l = *(const i32x4*)&Wl[t * 16 + lr][cb + lg * 8];
        mfma_b16(acc[t], a_h, b_h);
        mfma_b16(acc[t], a_h, b_l);
      }
    }
  }

  // cover MFMA->VALU write latency (asm is opaque to the scheduler)
  asm volatile("s_nop 7\n\ts_nop 7" ::);

#pragma unroll
  for (int t = 0; t < TNT; ++t) {
    int c = t * 16 + lr;
    float bv = bias ? bias[c] : 0.f;
#pragma unroll
    for (int q = 0; q < 4; ++q) {
      int r = row0 + wv * 16 + lg * 4 + q;
      if (r < nrows) {
        float v = acc[t][q] + bv;
        if (relu) v = fmaxf(v, 0.f);
        C[(size_t)r * BN + c] = f2bf_rne(v);
      }
    }
  }
}

// ---------------------------------------------------------------------------
// z = H @ Wnp^T + bnp  (H: [n,64] bf16, Wnp: [16,64] f32) then LayerNorm(16)
__global__ __launch_bounds__(256) void nodepred_ln_kernel(
    const unsigned short* __restrict__ H, const float* __restrict__ Wnp,
    const float* __restrict__ bnp, const float* __restrict__ g,
    const float* __restrict__ lb, float* __restrict__ out, int nrows) {
  __shared__ float hs[16][64];
  int tid = threadIdx.x;
  int row0 = blockIdx.x * 16;
  {
    int r = tid >> 4;
    int c4 = (tid & 15) << 2;
    int gr = row0 + r;
    float4 v = make_float4(0.f, 0.f, 0.f, 0.f);
    if (gr < nrows) v = bf4_to_f4(*(const uint2*)(H + (size_t)gr * 64 + c4));
    *(float4*)&hs[r][c4] = v;
  }
  __syncthreads();
  int r = tid >> 4, j = tid & 15;
  float z = bnp[j];
  const float* wrow = Wnp + j * 64;
#pragma unroll 8
  for (int k = 0; k < 64; ++k) z += hs[r][k] * wrow[k];
  float s = z, s2 = z * z;
#pragma unroll
  for (int m = 1; m < 16; m <<= 1) {
    s += __shfl_xor(s, m, 16);
    s2 += __shfl_xor(s2, m, 16);
  }
  float mu = s * (1.f / 16.f);
  float var = s2 * (1.f / 16.f) - mu * mu;
  float o = (z - mu) * rsqrtf(var + EPS_LN) * g[j] + lb[j];
  int gr = row0 + r;
  if (gr < nrows) out[(size_t)gr * 16 + j] = o;
}

// ---------------------------------------------------------------------------
// out1[i] = f32(R_bf16[mn[i]]), out2[i] = X_f32[mn[i]]   (rows of 128)
__global__ __launch_bounds__(256) void gather_out_kernel(
    const int* __restrict__ mn, const unsigned short* __restrict__ R,
    const float* __restrict__ X,
    float* __restrict__ o1, float* __restrict__ o2, int nmask) {
  int gid = blockIdx.x * 256 + threadIdx.x;
  if (gid >= nmask * 32) return;
  int i = gid >> 5, c4 = (gid & 31) << 2;
  int r = mn[i];
  float4 rv = bf4_to_f4(*(const uint2*)(R + (size_t)r * 128 + c4));
  *(float4*)(o1 + (size_t)i * 128 + c4) = rv;
  *(float4*)(o2 + (size_t)i * 128 + c4) = *(const float4*)(X + (size_t)r * 128 + c4);
}

// ---------------------------------------------------------------------------
static void launch_gemm(const unsigned short* A1, const unsigned short* Wh1,
                        const unsigned short* Wl1, int k1,
                        const unsigned short* A2, const unsigned short* Wh2,
                        const unsigned short* Wl2, int k2,
                        const float* bias, int relu,
                        unsigned short* C, int m, int nrows, hipStream_t s) {
  int blocks = (nrows + 63) / 64;
  switch (m) {
    case 128:
      mfma_gemm_kernel<8><<<blocks, 256, 0, s>>>(A1, Wh1, Wl1, k1, A2, Wh2, Wl2, k2,
                                                 bias, relu, C, nrows);
      break;
    case 96:
      mfma_gemm_kernel<6><<<blocks, 256, 0, s>>>(A1, Wh1, Wl1, k1, A2, Wh2, Wl2, k2,
                                                 bias, relu, C, nrows);
      break;
    case 64:
      mfma_gemm_kernel<4><<<blocks, 256, 0, s>>>(A1, Wh1, Wl1, k1, A2, Wh2, Wl2, k2,
                                                 bias, relu, C, nrows);
      break;
  }
}

extern "C" void kernel_launch(void* const* d_in, const int* in_sizes, int n_in,
                              void* d_out, int out_size, void* d_ws, size_t ws_size,
                              hipStream_t stream) {
  const float* x = (const float*)d_in[0];
  const int* src = (const int*)d_in[1];
  const int* dst = (const int*)d_in[2];
  const float* ew = (const float*)d_in[3];
  const int* mn = (const int*)d_in[4];
  const float* token = (const float*)d_in[5];

  const float* W[20];
  for (int i = 0; i < 20; ++i) W[i] = (const float*)d_in[6 + i];
  const float* W_e2d = (const float*)d_in[26];
  const float* Wnp = (const float*)d_in[27];
  const float* bnp = (const float*)d_in[28];
  const float* ln_g = (const float*)d_in[29];
  const float* ln_b = (const float*)d_in[30];

  const int Nn = in_sizes[0] / 128;   // 50000
  const int E = in_sizes[1];          // 600000
  const int nmask = in_sizes[4];      // 10000
  const int nb = (Nn + SCAN_CHUNK - 1) / SCAN_CHUNK;  // 49

  // workspace layout (bf16 activations)
  unsigned short* bufA = (unsigned short*)d_ws;            // N*128 bf16
  unsigned short* bufB = bufA + (size_t)Nn * 128;          // N*128 bf16
  unsigned short* pool16 = bufB + (size_t)Nn * 128;        // N*128 bf16
  unsigned short* neigh16 = pool16 + (size_t)Nn * 128;     // N*128 bf16
  int* deg = (int*)(neigh16 + (size_t)Nn * 128);           // N int
  int* cur = deg + Nn;                                     // N int
  int2* esw = (int2*)(cur + Nn);                           // E int2
  int* off = (int*)(esw + E);                              // N+1 int
  int* bsum = off + Nn + 1;                                // 64 int
  int* bbase = bsum + 64;                                  // 64 int
  float* WpP = (float*)(bbase + 64);                       // 64*64 f32
  float* WsP = WpP + 64 * 64;                              // 96*64 f32
  unsigned short* wplanes =
      (unsigned short*)(((uintptr_t)(WsP + 96 * 64) + 15) & ~(uintptr_t)15);

  // ---- fold encoder_to_decoder into dec0 weights (tiny) ----
  matmul_small_kernel<<<(64 * 64 + 255) / 256, 256, 0, stream>>>(W[10], W_e2d, WpP, 64, 64, 64);
  matmul_small_kernel<<<(96 * 64 + 255) / 256, 256, 0, stream>>>(W[12], W_e2d, WsP, 96, 64, 64);

  // ---- one-shot split of all GEMM weights into bf16 hi/lo planes ----
  const int msz[12] = {128 * 128, 96 * 128, 96 * 128, 96 * 96, 64 * 96, 64 * 96,
                       64 * 64,  96 * 64,  96 * 64,  96 * 96, 128 * 96, 128 * 96};
  const float* msrc[12] = {W[0], W[2], W[3], W[5], W[7], W[8],
                           WpP,  WsP,  W[13], W[15], W[17], W[18]};
  int mtot = 0;
  int moff[12];
  for (int i = 0; i < 12; ++i) { moff[i] = mtot; mtot += msz[i]; }
  unsigned short* wh_[12];
  unsigned short* wl_[12];
  SplitWArgs sa;
  for (int i = 0; i < 12; ++i) {
    wh_[i] = wplanes + moff[i];
    wl_[i] = wplanes + mtot + moff[i];
    sa.src[i] = msrc[i];
    sa.dh[i] = wh_[i];
    sa.dl[i] = wl_[i];
    sa.n[i] = msz[i];
  }
  {
    dim3 grid((128 * 128 / 4 + 255) / 256, 12);
    split_w_kernel<<<grid, 256, 0, stream>>>(sa);
  }

  // ---- CSR build (once; graph identical across layers) ----
  hipMemsetAsync(deg, 0, (size_t)Nn * 2 * sizeof(int), stream);  // deg + cur
  hist_kernel<<<(E + 255) / 256, 256, 0, stream>>>(dst, deg, E);
  blocksum_kernel<<<nb, 256, 0, stream>>>(deg, bsum, Nn);
  bscan_kernel<<<1, 64, 0, stream>>>(bsum, bbase, off + Nn, nb);
  chunkscan_kernel<<<nb, 256, 0, stream>>>(deg, bbase, off, Nn);
  scatter_kernel<<<(E + 255) / 256, 256, 0, stream>>>(src, dst, ew, off, cur, esw, E);

  // h = bf16(x); h[mask_nodes] = bf16(token)
  {
    int n4 = Nn * 128 / 4;
    copy_bf16_kernel<<<(n4 + 255) / 256, 256, 0, stream>>>((const float4*)x, (uint2*)bufA, n4);
    mask_scatter_kernel<<<(nmask * 32 + 255) / 256, 256, 0, stream>>>(mn, token, bufA, nmask);
  }

  // plane indices {wp, ws, wn} per layer
  auto run_sage = [&](int ip, int is, int in_, const float* bp, const float* b,
                      int din, int dout) {
    // p = relu(h @ Wp^T + bp)  -> bf16 pool
    launch_gemm(bufA, wh_[ip], wl_[ip], din, nullptr, nullptr, nullptr, 0,
                bp, 1, pool16, din, Nn, stream);
    // neigh = segment_max(p[src]*ew, dst), bf16; zero-degree rows -> 0
    int lanes = din >> 3;
    long long tot = (long long)Nn * lanes;
    int nblocks = (int)((tot + 255) / 256);
    neigh_csr_kernel<<<nblocks, 256, 0, stream>>>(pool16, off, esw, neigh16, din, lanes, Nn);
    // out = relu(h @ Ws^T + neigh @ Wn^T + b)  -> bf16
    launch_gemm(bufA, wh_[is], wl_[is], din, neigh16, wh_[in_], wl_[in_], din,
                b, 1, bufB, dout, Nn, stream);
    unsigned short* t = bufA; bufA = bufB; bufB = t;
  };

  // encoder
  run_sage(0, 1, 2, W[1], W[4], 128, 96);   // enc0
  run_sage(3, 4, 5, W[6], W[9], 96, 64);    // enc1

  // node_pred + layernorm -> n_scores (out section 3)
  float* out_r = (float*)d_out;
  float* out_x = out_r + (size_t)nmask * 128;
  float* out_ns = out_x + (size_t)nmask * 128;
  nodepred_ln_kernel<<<(Nn + 15) / 16, 256, 0, stream>>>(bufA, Wnp, bnp, ln_g, ln_b, out_ns, Nn);

  // decoder (e2d folded into dec0 weights)
  run_sage(6, 7, 8, W[11], W[14], 64, 96);     // dec0 (+e2d)
  run_sage(9, 10, 11, W[16], W[19], 96, 128);  // dec1

  // outputs 1 & 2
  gather_out_kernel<<<(nmask * 32 + 255) / 256, 256, 0, stream>>>(mn, bufA, x, out_r, out_x, nmask);
}